// Round 3
// baseline (4678.701 us; speedup 1.0000x reference)
//
#include <hip/hip_runtime.h>
#include <math.h>

#define N   257     // state dim
#define AP  258     // augmented row length (cols 0..256 = S, col 257 = rhs)
#define MM  128     // rotation pairs
#define LL  512     // seq length
#define BB  4       // batch
#define NB  32      // panel width
#define PSTR 260    // panel LDS column stride
#define TCP  228    // U12 LDS row stride

// workspace layout (float offsets)
#define OFF_A  0        // N*AP = 66306 floats
#define OFF_W0 66308    // 257 floats
#define OFF_TH 66568    // B*L*M = 262144 floats

// Block 0: solve S w0 = z0 via panel-blocked Gauss-Jordan (perm indirection).
// Invariant after panel p: every row's entries in panel-p columns are
// eliminated EXCEPT the within-panel upper-triangular U11 of p's pivot rows.
// Finish therefore needs per-panel 32-step back-substitution (not a diagonal
// solve) — U11 is written back to A in step 3 to make that possible.
// Blocks 1..4: per-batch angle cumsum (fp64 accumulator).
__global__ __launch_bounds__(1024) void prep_kernel(const float* __restrict__ x,
                                                    const float* __restrict__ z0,
                                                    const float* __restrict__ om,
                                                    const float* __restrict__ S,
                                                    float* __restrict__ ws) {
  __shared__ __align__(16) float P[NB * PSTR];
  __shared__ __align__(16) float U12[NB * TCP];
  __shared__ int   perm[N];
  __shared__ float redv[16];
  __shared__ int   redi[16];
  __shared__ float xs[N];      // final solution
  __shared__ float rr[256];    // running residual for back-substitution

  const int tid = threadIdx.x;
  float* A  = ws + OFF_A;
  float* w0 = ws + OFF_W0;

  if (blockIdx.x != 0) {
    // ---- angle cumsum for batch b ----
    const int b = blockIdx.x - 1;
    float* xsh = P;  // reuse LDS
    for (int idx = tid; idx < LL * 2; idx += 1024) xsh[idx] = x[b * LL * 2 + idx];
    __syncthreads();
    if (tid < MM) {
      const float om0 = om[2 * tid], om1 = om[2 * tid + 1];
      double acc = 0.0;
      float* th = ws + OFF_TH + (size_t)b * LL * MM + tid;
      for (int l = 0; l < LL; ++l) {
        acc += (double)(xsh[2 * l] * om0 + xsh[2 * l + 1] * om1);
        th[(size_t)l * MM] = (float)acc;
      }
    }
    return;
  }

  // ---- stage augmented [S | z0] and init perm ----
  for (int idx = tid; idx < N * N; idx += 1024) {
    int i = idx / N, j = idx - i * N;
    A[i * AP + j] = S[idx];
  }
  for (int i = tid; i < N; i += 1024) { A[i * AP + N] = z0[i]; perm[i] = i; }
  __syncthreads();

  for (int p = 0; p < 8; ++p) {
    const int k0 = p * NB;
    const int ct = k0 + NB;
    const int tc = (N + 1) - ct;

    // 1. load panel columns (ALL rows, perm-indirect) into LDS, column-major
    for (int idx = tid; idx < N * NB; idx += 1024) {
      const int i = idx >> 5, c = idx & 31;
      P[c * PSTR + i] = A[perm[i] * AP + k0 + c];
    }
    __syncthreads();

    // 2. factor rows [k0,N) with partial pivoting (all in LDS)
    for (int j = 0; j < NB; ++j) {
      const int d = k0 + j;
      const int nrows = N - d;
      float v = -1.0f; int vi = d;
      if (tid < nrows) { vi = d + tid; v = fabsf(P[j * PSTR + vi]); }
      #pragma unroll
      for (int off = 1; off < 64; off <<= 1) {
        const float ov = __shfl_xor(v, off);
        const int   oi = __shfl_xor(vi, off);
        if (ov > v) { v = ov; vi = oi; }
      }
      if ((tid & 63) == 0) { redv[tid >> 6] = v; redi[tid >> 6] = vi; }
      __syncthreads();
      {
        float bv = redv[0]; int bi = redi[0];
        #pragma unroll
        for (int w = 1; w < 16; ++w) if (redv[w] > bv) { bv = redv[w]; bi = redi[w]; }
        if (tid == 0 && bi != d) { const int t = perm[d]; perm[d] = perm[bi]; perm[bi] = t; }
        if (tid < NB && bi != d) {
          const float a2 = P[tid * PSTR + d], b2 = P[tid * PSTR + bi];
          P[tid * PSTR + d] = b2; P[tid * PSTR + bi] = a2;
        }
      }
      __syncthreads();
      const float pinv = 1.0f / P[j * PSTR + d];
      if (tid < nrows - 1) {
        const int i = d + 1 + tid;
        const float m = P[j * PSTR + i] * pinv;
        P[j * PSTR + i] = m;
        #pragma unroll 4
        for (int j2 = j + 1; j2 < NB; ++j2)
          P[j2 * PSTR + i] -= m * P[j2 * PSTR + d];
      }
      __syncthreads();
    }

    // 3. write back FULL U11 upper triangle (row pos j, col t, t>=j).
    //    Nothing later reads/writes pivot rows' panel columns, so no race
    //    with steps 4-6 (they touch trailing columns / LDS only).
    for (int idx = tid; idx < NB * NB; idx += 1024) {
      const int j = idx >> 5, t = idx & 31;
      if (t >= j) A[perm[k0 + j] * AP + (k0 + t)] = P[t * PSTR + (k0 + j)];
    }

    // 4+5. U12 = L11^-1 * A12 (threads [0,tc)) and M01 = A01 * U11^-1
    //      (threads [512,512+k0)) — disjoint data, run concurrently.
    if (tid < tc) {
      const int c = tid;
      float u[NB];
      #pragma unroll
      for (int jr = 0; jr < NB; ++jr) {
        float vv = A[perm[k0 + jr] * AP + ct + c];
        for (int t = 0; t < jr; ++t) vv -= P[t * PSTR + (k0 + jr)] * u[t];
        u[jr] = vv;
        U12[jr * TCP + c] = vv;
        A[perm[k0 + jr] * AP + ct + c] = vv;
      }
    } else if (tid >= 512 && tid < 512 + k0) {
      const int r = tid - 512;
      float m[NB];
      #pragma unroll
      for (int j = 0; j < NB; ++j) {
        float vv = P[j * PSTR + r];
        for (int t = 0; t < j; ++t) vv -= m[t] * P[j * PSTR + (k0 + t)];
        vv /= P[j * PSTR + (k0 + j)];
        m[j] = vv;
      }
      #pragma unroll
      for (int j = 0; j < NB; ++j) P[j * PSTR + r] = m[j];
    }
    __syncthreads();

    // 6. trailing GEMM: rows [0,k0) U [ct,N), cols [ct,258)
    {
      const int ntc = (tc + 3) >> 2;
      #pragma unroll
      for (int reg = 0; reg < 2; ++reg) {
        const int rbase = reg ? ct : 0;
        const int rend  = reg ? N  : k0;
        const int nr = rend - rbase;
        if (nr > 0) {
          const int ntr = (nr + 3) >> 2;
          for (int tI = tid; tI < ntr * ntc; tI += 1024) {
            const int trr = tI / ntc, tcc2 = tI - trr * ntc;
            const int i0 = rbase + trr * 4, c0 = tcc2 * 4;
            int prow[4]; bool rok[4];
            #pragma unroll
            for (int r = 0; r < 4; ++r) {
              rok[r] = (i0 + r) < rend;
              prow[r] = rok[r] ? perm[i0 + r] : 0;
            }
            float acc[4][4];
            #pragma unroll
            for (int r = 0; r < 4; ++r)
              #pragma unroll
              for (int c = 0; c < 4; ++c)
                acc[r][c] = (rok[r] && (c0 + c) < tc) ? A[prow[r] * AP + ct + c0 + c] : 0.0f;
            #pragma unroll
            for (int t = 0; t < NB; ++t) {
              const float4 pv = *(const float4*)(P + t * PSTR + i0);
              const float4 uv = *(const float4*)(U12 + t * TCP + c0);
              acc[0][0] -= pv.x * uv.x; acc[0][1] -= pv.x * uv.y; acc[0][2] -= pv.x * uv.z; acc[0][3] -= pv.x * uv.w;
              acc[1][0] -= pv.y * uv.x; acc[1][1] -= pv.y * uv.y; acc[1][2] -= pv.y * uv.z; acc[1][3] -= pv.y * uv.w;
              acc[2][0] -= pv.z * uv.x; acc[2][1] -= pv.z * uv.y; acc[2][2] -= pv.z * uv.z; acc[2][3] -= pv.z * uv.w;
              acc[3][0] -= pv.w * uv.x; acc[3][1] -= pv.w * uv.y; acc[3][2] -= pv.w * uv.z; acc[3][3] -= pv.w * uv.w;
            }
            #pragma unroll
            for (int r = 0; r < 4; ++r)
              #pragma unroll
              for (int c = 0; c < 4; ++c)
                if (rok[r] && (c0 + c) < tc) A[prow[r] * AP + ct + c0 + c] = acc[r][c];
          }
        }
      }
    }
    __syncthreads();
  }

  // ---- finish: x256, then 8 independent per-panel back-substitutions ----
  if (tid == 0) {
    const int pr = perm[256];
    xs[256] = A[pr * AP + 257] / A[pr * AP + 256];
  }
  __syncthreads();
  const float x256 = xs[256];
  int pr_t = 0;
  if (tid < 256) {
    pr_t = perm[tid];
    rr[tid] = A[pr_t * AP + 257] - A[pr_t * AP + 256] * x256;
  }
  __syncthreads();
  // thread tid<256: panel p = tid>>5, within-panel position s = tid&31,
  // owns unknown x[k0+s] where row = perm[k0+s] (pr_t).
  const int fp_k0 = (tid >> 5) << 5;   // k0 of this thread's panel
  const int fs    = tid & 31;
  for (int j = 31; j >= 0; --j) {
    if (tid < 256 && fs == j)
      xs[fp_k0 + j] = rr[fp_k0 + j] / A[pr_t * AP + (fp_k0 + j)];
    __syncthreads();
    if (tid < 256 && fs < j)
      rr[fp_k0 + fs] -= A[pr_t * AP + (fp_k0 + j)] * xs[fp_k0 + j];
    __syncthreads();
  }
  for (int k = tid; k < N; k += 1024) w0[k] = xs[k];
}

// out[(b,l), i] = sum_d S[i,d] * W[(b,l), d]
// W[.,0]=w0[0]; W[.,2m+1]=c*w0[2m+1]-s*w0[2m+2]; W[.,2m+2]=s*w0[2m+1]+c*w0[2m+2]
#define NL 8
__global__ __launch_bounds__(320) void combine_kernel(const float* __restrict__ S,
                                                      const float* __restrict__ ws,
                                                      float* __restrict__ out) {
  const int tid = threadIdx.x;
  const int b  = blockIdx.y;
  const int l0 = blockIdx.x * NL;
  const float* w0 = ws + OFF_W0;
  const float* th = ws + OFF_TH;
  __shared__ float Wl[NL][N];

  for (int idx = tid; idx < NL * N; idx += 320) {
    const int r = idx / N;
    const int d = idx - r * N;
    const int l = l0 + r;
    float v;
    if (d == 0) {
      v = w0[0];
    } else {
      const int m = (d - 1) >> 1;
      const int pq = 2 * m + 1;
      const float t = th[(size_t)(b * LL + l) * MM + m];
      float s, c;
      sincosf(t, &s, &c);
      const float a0 = w0[pq], a1 = w0[pq + 1];
      v = (d & 1) ? (c * a0 - s * a1) : (s * a0 + c * a1);
    }
    Wl[r][d] = v;
  }
  __syncthreads();

  const int i = tid;
  if (i < N) {
    const float* Si = S + (size_t)i * N;
    float acc[NL];
    #pragma unroll
    for (int r = 0; r < NL; ++r) acc[r] = 0.0f;
    #pragma unroll 4
    for (int d = 0; d < N; ++d) {
      const float sv = Si[d];
      #pragma unroll
      for (int r = 0; r < NL; ++r) acc[r] += sv * Wl[r][d];
    }
    const size_t base = (size_t)(b * LL + l0) * N + i;
    #pragma unroll
    for (int r = 0; r < NL; ++r) out[base + (size_t)r * N] = acc[r];
    if (l0 + NL == LL) {
      out[(size_t)BB * LL * N + (size_t)b * N + i] = acc[NL - 1];
    }
  }
}

extern "C" void kernel_launch(void* const* d_in, const int* in_sizes, int n_in,
                              void* d_out, int out_size, void* d_ws, size_t ws_size,
                              hipStream_t stream) {
  const float* x  = (const float*)d_in[0];   // (B, L, 2)
  const float* z0 = (const float*)d_in[1];   // (D,)
  const float* om = (const float*)d_in[2];   // (M, 2)
  const float* S  = (const float*)d_in[3];   // (D, D)
  float* ws  = (float*)d_ws;
  float* out = (float*)d_out;                // outputs (B,L,D) then z_final (B,D)

  hipLaunchKernelGGL(prep_kernel, dim3(1 + BB), dim3(1024), 0, stream, x, z0, om, S, ws);
  hipLaunchKernelGGL(combine_kernel, dim3(LL / NL, BB), dim3(320), 0, stream, S, ws, out);
}